// Round 1
// baseline (172.940 us; speedup 1.0000x reference)
//
#include <hip/hip_runtime.h>
#include <cmath>

// RestorationLoss = (1 - mean(SSIM(r_low, r_high))) + mean((r_low - r_high)^2)
// Separable 11x11 gaussian; 4 conv fields: mu1, mu2, S=conv(a^2+b^2), P=conv(ab).
// out = 1 + sum(d^2 - ssim_px)/N.
// R12 = R11 skeleton with TILE_H 16 -> 32 (VALU-amortization round):
//  - staging redundancy (TILE_H+10)/TILE_H: 1.625 -> 1.3125 (-19% phase-1 conv)
//  - phase-2 ds_read_b128 per output px: 3.5 -> 2.25 (18 reads / 8 px)
//  - per-block fixed cost halved (12288 -> 6144 blocks)
// LDS 43.7 KB -> still 3 blocks/CU (same as measured 38% occupancy at R11).
// Frozen from R11: interleaved padded hbuf[.][65] float4 layout, rcp-based
// ssim epilogue, float4-aligned conditional edge loads, 256 thr,
// launch_bounds(256,3), R9-style load/conv software pipeline.

#define HH 512
#define WW 512
#define TILE_H 32
#define TILE_W 64
#define HB (TILE_H + 10)                          // 42 staged rows
#define LDW 65                                    // padded row: 65 float4s
#define NPLANES 48
#define CT (WW / TILE_W)                          // 8
#define RT (HH / TILE_H)                          // 16
#define NBLOCKS (NPLANES * RT * CT)               // 6144

struct GW { float g[11]; };

__global__ __launch_bounds__(256, 3)
void ssim_main(const float* __restrict__ img1, const float* __restrict__ img2,
               float* __restrict__ partial, GW gw)
{
    __shared__ float4 hbuf[HB][LDW];              // interleaved (mu1,mu2,S,P): 43680 B
    __shared__ float red[4];

    const int tid   = threadIdx.x;
    const int bx    = blockIdx.x;
    const int by    = blockIdx.y;
    const int plane = blockIdx.z;
    const int row0  = by * TILE_H;
    const int col0  = bx * TILE_W;
    const float* p1 = img1 + (size_t)plane * (HH * WW);
    const float* p2 = img2 + (size_t)plane * (HH * WW);

    const int cg    = tid & 15;                   // col group: tile cols 4cg..4cg+3
    const int rs    = tid >> 4;                   // 0..15
    const int cbase = col0 + 4 * cg - 8;          // 20-float window, 16B aligned

    // 5 conditional float4 loads; OOB vectors become zeros (valid: all OOB col
    // spans are float4-aligned since cbase%4==0 and limits 0/512 are too)
    auto loadRow = [&](int grow, float4* x1, float4* x2) {
        const int growc = min(max(grow, 0), HH - 1);      // always in-bounds
        const float* r1 = p1 + (size_t)growc * WW;
        const float* r2 = p2 + (size_t)growc * WW;
        #pragma unroll
        for (int v = 0; v < 5; ++v) {
            const int c0 = cbase + 4 * v;
            if (c0 >= 0 && c0 + 4 <= WW) {
                x1[v] = *reinterpret_cast<const float4*>(r1 + c0);
                x2[v] = *reinterpret_cast<const float4*>(r2 + c0);
            } else {
                x1[v] = make_float4(0.f, 0.f, 0.f, 0.f);
                x2[v] = make_float4(0.f, 0.f, 0.f, 0.f);
            }
        }
    };

    // horizontal conv of one staged row -> interleaved hbuf[rl][col]
    auto convStore = [&](int rl, const float4* x1v, const float4* x2v) {
        const int   grow  = row0 - 5 + rl;
        const float rmask = (grow >= 0 && grow < HH) ? 1.f : 0.f;
        const float* x1 = reinterpret_cast<const float*>(x1v);
        const float* x2 = reinterpret_cast<const float*>(x2v);
        float acc[4][4];
        #pragma unroll
        for (int k = 0; k < 4; ++k)
            #pragma unroll
            for (int i = 0; i < 4; ++i) acc[k][i] = 0.f;
        #pragma unroll
        for (int e = 3; e <= 16; ++e) {           // out col i uses e = i+j+3
            float a  = x1[e], b = x2[e];
            float v2 = a * a + b * b;
            float v3 = a * b;
            #pragma unroll
            for (int i = 0; i < 4; ++i) {
                int j = e - 3 - i;
                if (j >= 0 && j < 11) {
                    float w = gw.g[j];
                    acc[0][i] += w * a;
                    acc[1][i] += w * b;
                    acc[2][i] += w * v2;
                    acc[3][i] += w * v3;
                }
            }
        }
        // row-OOB rows contribute zero (all 4 fields vanish on zero inputs)
        #pragma unroll
        for (int i = 0; i < 4; ++i)
            hbuf[rl][4 * cg + i] =
                make_float4(acc[0][i] * rmask, acc[1][i] * rmask,
                            acc[2][i] * rmask, acc[3][i] * rmask);
    };

    // ---- Phase 1: software-pipelined; 42 rows = 16 + 16 + 10 ----
    {
        float4 xA1[5], xA2[5], xB1[5], xB2[5];
        const bool third = (rs < 10);
        loadRow(row0 - 5 + rs, xA1, xA2);         // rows 0..15
        loadRow(row0 + 11 + rs, xB1, xB2);        // rows 16..31
        convStore(rs, xA1, xA2);                  // under B's load latency
        if (third) loadRow(row0 + 27 + rs, xA1, xA2);  // rows 32..41 (reuse A regs)
        convStore(rs + 16, xB1, xB2);             // under C's load latency
        if (third) convStore(rs + 32, xA1, xA2);
    }

    // ---- MSE pixel prefetch (no LDS dependence; consumed after barrier) ----
    const int tx = tid & 63;                      // column
    const int rg = tid >> 6;                      // 0..3 -> rows 8rg..8rg+7
    float mse_a[8], mse_b[8];
    #pragma unroll
    for (int p = 0; p < 8; ++p) {
        size_t off = (size_t)(row0 + rg * 8 + p) * WW + col0 + tx;
        mse_a[p] = p1[off];
        mse_b[p] = p2[off];
    }
    __syncthreads();

    // ---- Phase 2: vertical conv (18 b128 reads / 8 rows) + ssim + mse ----
    float local = 0.f;
    {
        float4 res[8];
        #pragma unroll
        for (int p = 0; p < 8; ++p) res[p] = make_float4(0.f, 0.f, 0.f, 0.f);
        #pragma unroll
        for (int j = 0; j < 18; ++j) {            // window rows rg*8 .. rg*8+17
            float4 w4 = hbuf[rg * 8 + j][tx];
            #pragma unroll
            for (int p = 0; p < 8; ++p) {
                int t = j - p;
                if (t >= 0 && t < 11) {
                    float w = gw.g[t];
                    res[p].x += w * w4.x;
                    res[p].y += w * w4.y;
                    res[p].z += w * w4.z;
                    res[p].w += w * w4.w;
                }
            }
        }
        const float C1c = 0.0001f, C2c = 0.0009f;
        #pragma unroll
        for (int p = 0; p < 8; ++p) {
            float mu1 = res[p].x, mu2 = res[p].y;
            float S   = res[p].z, P   = res[p].w;
            float m11 = mu1 * mu1, m22 = mu2 * mu2, m12 = mu1 * mu2;
            float num = (2.f * m12 + C1c) * (2.f * (P - m12) + C2c);
            float den = (m11 + m22 + C1c) * ((S - m11 - m22) + C2c);
            float inv = __builtin_amdgcn_rcpf(den);   // ~1ulp, fine vs 2.3e-2
            float d   = mse_a[p] - mse_b[p];
            local += d * d - num * inv;
        }
    }

    // ---- block reduce ----
    #pragma unroll
    for (int off = 32; off > 0; off >>= 1) local += __shfl_down(local, off);
    if ((tid & 63) == 0) red[tid >> 6] = local;
    __syncthreads();
    if (tid == 0) {
        int bid = (plane * RT + by) * CT + bx;
        partial[bid] = (red[0] + red[1]) + (red[2] + red[3]);
    }
}

__global__ __launch_bounds__(256)
void ssim_finish(const float* __restrict__ partial, float* __restrict__ out)
{
    __shared__ float red[256];
    float s = 0.f;
    #pragma unroll
    for (int i = 0; i < NBLOCKS / 256; ++i)       // 24 independent loads
        s += partial[i * 256 + threadIdx.x];
    red[threadIdx.x] = s;
    __syncthreads();
    for (int step = 128; step > 0; step >>= 1) {
        if ((int)threadIdx.x < step) red[threadIdx.x] += red[threadIdx.x + step];
        __syncthreads();
    }
    if (threadIdx.x == 0)
        out[0] = 1.0f + red[0] * (1.0f / 12582912.0f);
}

extern "C" void kernel_launch(void* const* d_in, const int* in_sizes, int n_in,
                              void* d_out, int out_size, void* d_ws, size_t ws_size,
                              hipStream_t stream)
{
    const float* r_low  = (const float*)d_in[0];
    const float* r_high = (const float*)d_in[1];
    float* out     = (float*)d_out;
    float* partial = (float*)d_ws;                       // 6144 floats = 24 KB

    GW gw;                                               // gaussian -> SGPRs
    {
        float s = 0.f;
        for (int i = 0; i < 11; ++i) {
            float c = (float)(i - 5);
            gw.g[i] = expf(-(c * c) / 4.5f);             // 2*sigma^2 = 4.5
            s += gw.g[i];
        }
        for (int i = 0; i < 11; ++i) gw.g[i] /= s;
    }

    dim3 grid(CT, RT, NPLANES);
    ssim_main<<<grid, dim3(256), 0, stream>>>(r_low, r_high, partial, gw);
    ssim_finish<<<1, dim3(256), 0, stream>>>(partial, out);
}

// Round 2
// 171.821 us; speedup vs baseline: 1.0065x; 1.0065x over previous
//
#include <hip/hip_runtime.h>
#include <cmath>

// RestorationLoss = (1 - mean(SSIM(r_low, r_high))) + mean((r_low - r_high)^2)
// Separable 11x11 gaussian; 4 conv fields: mu1, mu2, S=conv(a^2+b^2), P=conv(ab).
// out = 1 + sum(d^2 - ssim_px)/N.
// R13 = R12 skeleton reshaped for occupancy (R12 post-mortem: VALU work fell
// 20% but OccupancyPercent 38->29 ate it; 44KB LDS = 3 blocks/CU):
//  - TILE 64x32 -> 32 wide x 64 tall: hbuf[74][33] float4 = 39.1 KB
//    -> 4 blocks/CU (163840/39104=4.19), launch_bounds(256,4).
//  - vertical staging redundancy (TILE_H+10)/TILE_H: 1.3125 -> 1.156.
//  - phase-2 unchanged: 8-row strip/thread, 18 b128 reads / 8 px.
//  - rmask dropped: row-OOB folded into load zero-fill (== reference zero pad).
//  - MSE prefetch vectorized: 4 float4 loads (was 16 scalar).
// Frozen: interleaved padded float4 hbuf, rcp-based ssim epilogue,
// float4-aligned conditional edge loads, 256 thr, R9 load/conv pipeline.

#define HH 512
#define WW 512
#define TILE_H 64
#define TILE_W 32
#define HB (TILE_H + 10)                          // 74 staged rows
#define LDW 33                                    // padded row: 33 float4s
#define NPLANES 48
#define CT (WW / TILE_W)                          // 16
#define RT (HH / TILE_H)                          // 8
#define NBLOCKS (NPLANES * RT * CT)               // 6144

struct GW { float g[11]; };

__global__ __launch_bounds__(256, 4)
void ssim_main(const float* __restrict__ img1, const float* __restrict__ img2,
               float* __restrict__ partial, GW gw)
{
    __shared__ float4 hbuf[HB][LDW];              // interleaved (mu1,mu2,S,P): 39072 B
    __shared__ float red[4];

    const int tid   = threadIdx.x;
    const int bx    = blockIdx.x;
    const int by    = blockIdx.y;
    const int plane = blockIdx.z;
    const int row0  = by * TILE_H;
    const int col0  = bx * TILE_W;
    const float* p1 = img1 + (size_t)plane * (HH * WW);
    const float* p2 = img2 + (size_t)plane * (HH * WW);

    const int cg    = tid & 7;                    // col group: tile cols 4cg..4cg+3
    const int rs    = tid >> 3;                   // 0..31 row slot
    const int cbase = col0 + 4 * cg - 8;          // 20-float window, 16B aligned

    // 5 conditional float4 loads; OOB vectors (col OR row) become zeros.
    // Valid: all OOB col spans are float4-aligned since cbase%4==0 and the
    // 0/512 limits are too. Row-OOB zero-fill == reference zero padding.
    auto loadRow = [&](int grow, float4* x1, float4* x2) {
        const bool rowOK = (grow >= 0 && grow < HH);
        const int growc = min(max(grow, 0), HH - 1);      // addr always in-bounds
        const float* r1 = p1 + (size_t)growc * WW;
        const float* r2 = p2 + (size_t)growc * WW;
        #pragma unroll
        for (int v = 0; v < 5; ++v) {
            const int c0 = cbase + 4 * v;
            if (rowOK && c0 >= 0 && c0 + 4 <= WW) {
                x1[v] = *reinterpret_cast<const float4*>(r1 + c0);
                x2[v] = *reinterpret_cast<const float4*>(r2 + c0);
            } else {
                x1[v] = make_float4(0.f, 0.f, 0.f, 0.f);
                x2[v] = make_float4(0.f, 0.f, 0.f, 0.f);
            }
        }
    };

    // horizontal conv of one staged row -> interleaved hbuf[rl][col]
    auto convStore = [&](int rl, const float4* x1v, const float4* x2v) {
        const float* x1 = reinterpret_cast<const float*>(x1v);
        const float* x2 = reinterpret_cast<const float*>(x2v);
        float acc[4][4];
        #pragma unroll
        for (int k = 0; k < 4; ++k)
            #pragma unroll
            for (int i = 0; i < 4; ++i) acc[k][i] = 0.f;
        #pragma unroll
        for (int e = 3; e <= 16; ++e) {           // out col i uses e = i+j+3
            float a  = x1[e], b = x2[e];
            float v2 = a * a + b * b;
            float v3 = a * b;
            #pragma unroll
            for (int i = 0; i < 4; ++i) {
                int j = e - 3 - i;
                if (j >= 0 && j < 11) {
                    float w = gw.g[j];
                    acc[0][i] += w * a;
                    acc[1][i] += w * b;
                    acc[2][i] += w * v2;
                    acc[3][i] += w * v3;
                }
            }
        }
        #pragma unroll
        for (int i = 0; i < 4; ++i)
            hbuf[rl][4 * cg + i] =
                make_float4(acc[0][i], acc[1][i], acc[2][i], acc[3][i]);
    };

    // ---- Phase 1: software-pipelined; 74 rows = 32 + 32 + 10 ----
    {
        float4 xA1[5], xA2[5], xB1[5], xB2[5];
        const bool third = (rs < 10);
        loadRow(row0 - 5 + rs, xA1, xA2);         // rows 0..31
        loadRow(row0 + 27 + rs, xB1, xB2);        // rows 32..63
        convStore(rs, xA1, xA2);                  // under B's load latency
        if (third) loadRow(row0 + 59 + rs, xA1, xA2);  // rows 64..73 (reuse A regs)
        convStore(rs + 32, xB1, xB2);             // under C's load latency
        if (third) convStore(rs + 64, xA1, xA2);
    }

    // ---- MSE pixel prefetch, vectorized (no LDS dep; consumed after barrier)
    const int mc = (tid & 7) * 4;                 // float4 col
    const int mr = tid >> 3;                      // 0..31 -> rows 2mr, 2mr+1
    float4 mse_a[2], mse_b[2];
    #pragma unroll
    for (int q = 0; q < 2; ++q) {
        size_t off = (size_t)(row0 + 2 * mr + q) * WW + col0 + mc;
        mse_a[q] = *reinterpret_cast<const float4*>(p1 + off);
        mse_b[q] = *reinterpret_cast<const float4*>(p2 + off);
    }
    __syncthreads();

    // ---- Phase 2: vertical conv (18 b128 reads / 8 rows) + ssim + mse ----
    float local = 0.f;
    {
        const int tx = tid & 31;                  // pixel column
        const int rg = tid >> 5;                  // 0..7 -> rows 8rg..8rg+7
        float4 res[8];
        #pragma unroll
        for (int p = 0; p < 8; ++p) res[p] = make_float4(0.f, 0.f, 0.f, 0.f);
        #pragma unroll
        for (int j = 0; j < 18; ++j) {            // window rows rg*8 .. rg*8+17
            float4 w4 = hbuf[rg * 8 + j][tx];
            #pragma unroll
            for (int p = 0; p < 8; ++p) {
                int t = j - p;
                if (t >= 0 && t < 11) {
                    float w = gw.g[t];
                    res[p].x += w * w4.x;
                    res[p].y += w * w4.y;
                    res[p].z += w * w4.z;
                    res[p].w += w * w4.w;
                }
            }
        }
        const float C1c = 0.0001f, C2c = 0.0009f;
        #pragma unroll
        for (int p = 0; p < 8; ++p) {
            float mu1 = res[p].x, mu2 = res[p].y;
            float S   = res[p].z, P   = res[p].w;
            float m11 = mu1 * mu1, m22 = mu2 * mu2, m12 = mu1 * mu2;
            float num = (2.f * m12 + C1c) * (2.f * (P - m12) + C2c);
            float den = (m11 + m22 + C1c) * ((S - m11 - m22) + C2c);
            float inv = __builtin_amdgcn_rcpf(den);   // ~1ulp, fine vs 2.3e-2
            local -= num * inv;
        }
        // MSE on this thread's (different) 8 px — global sum, mapping-free
        #pragma unroll
        for (int q = 0; q < 2; ++q) {
            float dx = mse_a[q].x - mse_b[q].x;
            float dy = mse_a[q].y - mse_b[q].y;
            float dz = mse_a[q].z - mse_b[q].z;
            float dw = mse_a[q].w - mse_b[q].w;
            local += dx * dx + dy * dy + dz * dz + dw * dw;
        }
    }

    // ---- block reduce ----
    #pragma unroll
    for (int off = 32; off > 0; off >>= 1) local += __shfl_down(local, off);
    if ((tid & 63) == 0) red[tid >> 6] = local;
    __syncthreads();
    if (tid == 0) {
        int bid = (plane * RT + by) * CT + bx;
        partial[bid] = (red[0] + red[1]) + (red[2] + red[3]);
    }
}

__global__ __launch_bounds__(256)
void ssim_finish(const float* __restrict__ partial, float* __restrict__ out)
{
    __shared__ float red[256];
    float s = 0.f;
    #pragma unroll
    for (int i = 0; i < NBLOCKS / 256; ++i)       // 24 independent loads
        s += partial[i * 256 + threadIdx.x];
    red[threadIdx.x] = s;
    __syncthreads();
    for (int step = 128; step > 0; step >>= 1) {
        if ((int)threadIdx.x < step) red[threadIdx.x] += red[threadIdx.x + step];
        __syncthreads();
    }
    if (threadIdx.x == 0)
        out[0] = 1.0f + red[0] * (1.0f / 12582912.0f);
}

extern "C" void kernel_launch(void* const* d_in, const int* in_sizes, int n_in,
                              void* d_out, int out_size, void* d_ws, size_t ws_size,
                              hipStream_t stream)
{
    const float* r_low  = (const float*)d_in[0];
    const float* r_high = (const float*)d_in[1];
    float* out     = (float*)d_out;
    float* partial = (float*)d_ws;                       // 6144 floats = 24 KB

    GW gw;                                               // gaussian -> SGPRs
    {
        float s = 0.f;
        for (int i = 0; i < 11; ++i) {
            float c = (float)(i - 5);
            gw.g[i] = expf(-(c * c) / 4.5f);             // 2*sigma^2 = 4.5
            s += gw.g[i];
        }
        for (int i = 0; i < 11; ++i) gw.g[i] /= s;
    }

    dim3 grid(CT, RT, NPLANES);
    ssim_main<<<grid, dim3(256), 0, stream>>>(r_low, r_high, partial, gw);
    ssim_finish<<<1, dim3(256), 0, stream>>>(partial, out);
}